// Round 8
// baseline (305.203 us; speedup 1.0000x reference)
//
#include <hip/hip_runtime.h>

typedef unsigned long long u64;
typedef unsigned int u32;
typedef unsigned short u16;

#define BATCH 2048
#define DIM   64
#define QSIZE 131072
#define HALFB 1024

// qc layout: 4096 blocks of 32 queue rows. Each 8 KB block:
//   hi plane [chunk c=0..7][row r&31][16B]  at  b*8192 + c*512 + (r&31)*16
//   lo plane same + 4096
// chunk c holds elements k = c*8 .. c*8+7 of the row (bf16, 2B each).
// A wave's MFMA B-fragment load (lane = lh*32+l31 reads row l31, chunk kt*2+lh)
// is then base + kt*1024 + lane*16 -> one fully coalesced 1KB dwordx4.
#define BLKB 8192

typedef __attribute__((ext_vector_type(8)))  short short8;
typedef __attribute__((ext_vector_type(16))) float f32x16;
typedef __attribute__((ext_vector_type(4)))  float f32x4;

__device__ __forceinline__ u16 bf16rn(float f) {
  u32 b = __float_as_uint(f);
  return (u16)((b + 0x7FFFu + ((b >> 16) & 1u)) >> 16);
}
__device__ __forceinline__ float bf16tof(u16 h) {
  return __uint_as_float(((u32)h) << 16);
}

// prep: blocks 0..4095 convert fp32 queue -> bf16 hi/lo fragment-ordered qc
// (XCD-aligned remap) + zero argmax slots; blocks >= 4096 (big-ws path only)
// do the newq copy-with-substitution (possible because qc lives in d_ws and
// no longer aliases newq). One kernel = one BW-saturating pass.
__global__ void prep_kernel(const float* __restrict__ q, char* __restrict__ qc,
                            u64* __restrict__ ws, const float* __restrict__ x,
                            const int* __restrict__ ptr_in, float* __restrict__ newq)
{
  int bid = blockIdx.x;
  if (bid < 4096) {
    int raw = bid * 256 + threadIdx.x;
    if (raw < BATCH) ws[raw] = 0;
    int b = ((bid & 7) << 9) | (bid >> 3);   // bijective for 4096; XCD-aligned
    int tid = threadIdx.x;
    int r5 = tid >> 3;                   // row in block 0..31
    int c  = tid & 7;                    // chunk 0..7
    const float* src = q + (size_t)(b * 32 + r5) * DIM + c * 8;
    f32x4 v0 = *(const f32x4*)src;
    f32x4 v1 = *(const f32x4*)(src + 4);
    float vv[8] = {v0[0], v0[1], v0[2], v0[3], v1[0], v1[1], v1[2], v1[3]};
    short8 h, l;
#pragma unroll
    for (int j = 0; j < 8; ++j) {
      u16 hb = bf16rn(vv[j]);
      u16 lb = bf16rn(vv[j] - bf16tof(hb));
      h[j] = (short)hb;
      l[j] = (short)lb;
    }
    char* dst = qc + (size_t)b * BLKB + c * 512 + r5 * 16;
    *(short8*)(dst)        = h;
    *(short8*)(dst + 4096) = l;
  } else {
    int i = (bid - 4096) * 256 + threadIdx.x;   // float4 index
    int r = i >> 4;
    int c = i & 15;
    int ptr = *ptr_in;
    u32 off = (u32)(r - ptr) & (QSIZE - 1);
    float4 v = (off < HALFB) ? ((const float4*)x)[off * 16 + c]
                             : ((const float4*)q)[i];
    ((float4*)newq)[i] = v;
  }
}

// sim = x . q^T via 3-pass bf16 hi/lo MFMA, fused row-argmax.
// Barrier-free, LDS-free main loop. KEY CHANGE (R8): the two per-tile ms-chains
// are INTERLEAVED MFMA-by-MFMA in the instruction stream. Waves issue in order,
// so two serially-dependent 12-chains emitted back-to-back expose full
// dependent-MFMA latency (~140cy/link -> MfmaUtil pinned ~45% in R0..R7).
// Interleaving gives each wave 2 independent in-flight chains; with 2 waves/SIMD
// the matrix pipe sees 4 streams -> ~4x32cy of work per latency window.
// Per-accumulator MFMA order is unchanged -> numerics bit-identical.
// Argmax is deferred one tile (acc x4); index state is byte-packed tile ids
// (tpack, R5-verified) to stay within the 2-wave register budget.
__global__ __launch_bounds__(256, 2) void sim_argmax_kernel(
    const float* __restrict__ x, const char* __restrict__ qc,
    u64* __restrict__ ws)
{
  __shared__ u64 table[128 * 32];   // 32 KB, epilogue reduce only

  const int tid  = threadIdx.x;
  const int lane = tid & 63;
  const int wave = tid >> 6;
  const int wm   = wave & 1;    // m-half (64 rows)
  const int wn   = wave >> 1;   // col-half (1024 of 2048 cols)
  const int l31  = lane & 31;
  const int lh   = lane >> 5;

  // XCD swizzle: hw linear id -> xcd = hw&7; each XCD owns 8 column groups,
  // all 16 m-blocks of a group stay on that XCD's L2. Bijective for 1024 wgs.
  const int hw   = blockIdx.x + (blockIdx.y << 4);
  const int mx   = (hw >> 3) & 15;
  const int ycol = ((hw & 7) << 3) | (hw >> 7);
  const int mblk = mx * 128;
  const int colbase = ycol * 2048;            // 2048-row queue slice

  // wave's 32 fragment-blocks: colgroup slice + wn half (32 blocks of 32 rows)
  const char* wbase = qc + (size_t)colbase * 256 + (size_t)wn * 32 * BLKB;
  const u32 lane16 = (u32)lane * 16;

  // persistent A fragments: A[m = l31][k = kt*16 + lh*8 + j]
  short8 ah[2][4], al[2][4];
#pragma unroll
  for (int ms = 0; ms < 2; ++ms) {
    const float* xr = x + (size_t)(mblk + wm * 64 + ms * 32 + l31) * DIM;
#pragma unroll
    for (int kt = 0; kt < 4; ++kt) {
      const float* p = xr + kt * 16 + lh * 8;
      float4 v0 = *(const float4*)(p);
      float4 v1 = *(const float4*)(p + 4);
      float vv[8] = {v0.x, v0.y, v0.z, v0.w, v1.x, v1.y, v1.z, v1.w};
      short8 h, l;
#pragma unroll
      for (int i = 0; i < 8; ++i) {
        u16 hb = bf16rn(vv[i]);
        u16 lb = bf16rn(vv[i] - bf16tof(hb));
        h[i] = (short)hb;
        l[i] = (short)lb;
      }
      ah[ms][kt] = h;
      al[ms][kt] = l;
    }
  }

  float best[2][16];
  u32   tpack[2][4];   // byte-packed winning tile id per [ms][r]
#pragma unroll
  for (int ms = 0; ms < 2; ++ms) {
#pragma unroll
    for (int r = 0; r < 16; ++r) best[ms][r] = -3.0e38f;
#pragma unroll
    for (int r = 0; r < 4; ++r) tpack[ms][r] = 0;
  }

  short8 pAh[4], pAl[4], pBh[4], pBl[4];
  f32x16 aE0, aE1, aO0, aO1;   // even/odd tile accumulators, ms0/ms1

#define LOADB(BH, BL, T) do {                                     \
    const char* p_ = wbase + (size_t)(T) * BLKB + lane16;         \
    BH[0] = *(const short8*)(p_ +    0);                          \
    BH[1] = *(const short8*)(p_ + 1024);                          \
    BH[2] = *(const short8*)(p_ + 2048);                          \
    BH[3] = *(const short8*)(p_ + 3072);                          \
    BL[0] = *(const short8*)(p_ + 4096);                          \
    BL[1] = *(const short8*)(p_ + 5120);                          \
    BL[2] = *(const short8*)(p_ + 6144);                          \
    BL[3] = *(const short8*)(p_ + 7168);                          \
  } while (0)

  // Two independent 12-chains interleaved at MFMA granularity. Per-acc order
  // (kt asc; hh, lh, hl) identical to all verified kernels.
#define CHAINS2(A0, A1, BH, BL) do {                                           \
    _Pragma("unroll")                                                          \
    for (int r = 0; r < 16; ++r) { A0[r] = 0.0f; A1[r] = 0.0f; }               \
    _Pragma("unroll")                                                          \
    for (int kt = 0; kt < 4; ++kt) {                                           \
      A0 = __builtin_amdgcn_mfma_f32_32x32x16_bf16(ah[0][kt], BH[kt], A0, 0, 0, 0); \
      A1 = __builtin_amdgcn_mfma_f32_32x32x16_bf16(ah[1][kt], BH[kt], A1, 0, 0, 0); \
      A0 = __builtin_amdgcn_mfma_f32_32x32x16_bf16(al[0][kt], BH[kt], A0, 0, 0, 0); \
      A1 = __builtin_amdgcn_mfma_f32_32x32x16_bf16(al[1][kt], BH[kt], A1, 0, 0, 0); \
      A0 = __builtin_amdgcn_mfma_f32_32x32x16_bf16(ah[0][kt], BL[kt], A0, 0, 0, 0); \
      A1 = __builtin_amdgcn_mfma_f32_32x32x16_bf16(ah[1][kt], BL[kt], A1, 0, 0, 0); \
    }                                                                          \
  } while (0)

  // t scans ascending per (ms,r,lane); strict '>' keeps smallest tile id.
#define ARGMAX2(A0, A1, T) do {                                                \
    const u32 t_ = (u32)(T);                                                   \
    _Pragma("unroll")                                                          \
    for (int r = 0; r < 16; ++r) {                                             \
      u32 sh = (u32)((r & 3) * 8);                                             \
      u32 p0 = tpack[0][r >> 2];                                               \
      u32 i0 = (p0 & ~(0xFFu << sh)) | (t_ << sh);                             \
      bool c0 = A0[r] > best[0][r];                                            \
      best[0][r] = c0 ? A0[r] : best[0][r];                                    \
      tpack[0][r >> 2] = c0 ? i0 : p0;                                         \
      u32 p1 = tpack[1][r >> 2];                                               \
      u32 i1 = (p1 & ~(0xFFu << sh)) | (t_ << sh);                             \
      bool c1 = A1[r] > best[1][r];                                            \
      best[1][r] = c1 ? A1[r] : best[1][r];                                    \
      tpack[1][r >> 2] = c1 ? i1 : p1;                                         \
    }                                                                          \
  } while (0)

  // prologue: tiles 0,1
  LOADB(pAh, pAl, 0);
  LOADB(pBh, pBl, 1);
  CHAINS2(aE0, aE1, pAh, pAl);          // tile 0
  LOADB(pAh, pAl, 2);
  CHAINS2(aO0, aO1, pBh, pBl);          // tile 1
  ARGMAX2(aE0, aE1, 0);
  LOADB(pBh, pBl, 3);

  // main: tiles 2..29 in pairs; argmax one tile behind (fills chain latency)
#pragma unroll 1
  for (int t = 2; t < 30; t += 2) {
    CHAINS2(aE0, aE1, pAh, pAl);        // tile t
    ARGMAX2(aO0, aO1, t - 1);
    LOADB(pAh, pAl, t + 2);
    CHAINS2(aO0, aO1, pBh, pBl);        // tile t+1
    ARGMAX2(aE0, aE1, t);
    LOADB(pBh, pBl, t + 3);
  }

  // epilogue: tiles 30,31
  CHAINS2(aE0, aE1, pAh, pAl);          // tile 30
  ARGMAX2(aO0, aO1, 29);
  CHAINS2(aO0, aO1, pBh, pBl);          // tile 31
  ARGMAX2(aE0, aE1, 30);
  ARGMAX2(aO0, aO1, 31);

#undef LOADB
#undef CHAINS2
#undef ARGMAX2

  // block reduce: table[row 0..127][l31 0..31], two wn phases, 128-thread scan.
  // col reconstruction: col = colbase + wn*1024 + tile*32 + l31.
  if (wn == 0) {
#pragma unroll
    for (int ms = 0; ms < 2; ++ms)
#pragma unroll
      for (int r = 0; r < 16; ++r) {
        int row = wm * 64 + ms * 32 + (r & 3) + 8 * (r >> 2) + 4 * lh;
        u32 tb = (tpack[ms][r >> 2] >> ((r & 3) * 8)) & 0xFFu;
        u32 colr = (u32)(colbase + wn * 1024 + (int)tb * 32 + l31);
        u32 fb = __float_as_uint(best[ms][r]);
        fb = (fb & 0x80000000u) ? ~fb : (fb | 0x80000000u);
        table[row * 32 + l31] = ((u64)fb << 32) | (u32)(~colr);
      }
  }
  __syncthreads();
  if (wn == 1) {
#pragma unroll
    for (int ms = 0; ms < 2; ++ms)
#pragma unroll
      for (int r = 0; r < 16; ++r) {
        int row = wm * 64 + ms * 32 + (r & 3) + 8 * (r >> 2) + 4 * lh;
        u32 tb = (tpack[ms][r >> 2] >> ((r & 3) * 8)) & 0xFFu;
        u32 colr = (u32)(colbase + wn * 1024 + (int)tb * 32 + l31);
        u32 fb = __float_as_uint(best[ms][r]);
        fb = (fb & 0x80000000u) ? ~fb : (fb | 0x80000000u);
        u64 pk = ((u64)fb << 32) | (u32)(~colr);
        u64* slot = &table[row * 32 + l31];
        if (pk > *slot) *slot = pk;   // unique writer per slot in this phase
      }
  }
  __syncthreads();
  if (tid < 128) {
    u64 mx64 = 0;
    // rotated scan start per lane: avoids the 32-way stride-256B bank conflict
    for (int j0 = 0; j0 < 32; ++j0) {
      int j = (j0 + tid) & 31;
      u64 v = table[tid * 32 + j];
      mx64 = (v > mx64) ? v : mx64;
    }
    atomicMax(&ws[mblk + tid], mx64);
  }
}

// big-ws path tail: nn gather + ptr only (newq copy already done in prep).
__global__ void gather_kernel(const float* __restrict__ q,
                              const int* __restrict__ ptr_in,
                              const u64* __restrict__ ws,
                              float* __restrict__ nn, float* __restrict__ nptr)
{
  int t = blockIdx.x * 256 + threadIdx.x;  // 0 .. BATCH*DIM-1
  int b = t >> 6;
  int d = t & 63;
  u32 qidx = ~(u32)(ws[b]);
  nn[t] = q[(size_t)qidx * DIM + d];
  if (t == 0) *nptr = (float)(((*ptr_in) + HALFB) & (QSIZE - 1));
}

// fallback tail (qc aliases newq): copy-with-substitution + gather, as verified.
__global__ void finish_kernel(const float* __restrict__ x, const float* __restrict__ q,
                              const int* __restrict__ ptr_in, const u64* __restrict__ ws,
                              float* __restrict__ nn, float* __restrict__ newq,
                              float* __restrict__ nptr)
{
  int bid = blockIdx.x;
  if (bid < 8192) {
    int i = bid * 256 + threadIdx.x;   // float4 index
    int r = i >> 4;
    int c = i & 15;
    int ptr = *ptr_in;
    u32 off = (u32)(r - ptr) & (QSIZE - 1);
    float4 v = (off < HALFB) ? ((const float4*)x)[off * 16 + c]
                             : ((const float4*)q)[i];
    ((float4*)newq)[i] = v;
  } else {
    int t = (bid - 8192) * 256 + threadIdx.x;
    int b = t >> 6;
    int d = t & 63;
    u32 qidx = ~(u32)(ws[b]);
    nn[t] = q[(size_t)qidx * DIM + d];
    if (t == 0) *nptr = (float)(((*ptr_in) + HALFB) & (QSIZE - 1));
  }
}

extern "C" void kernel_launch(void* const* d_in, const int* in_sizes, int n_in,
                              void* d_out, int out_size, void* d_ws, size_t ws_size,
                              hipStream_t stream)
{
  const float* x   = (const float*)d_in[0];
  const float* qx  = (const float*)d_in[1];
  const int*   ptr = (const int*)d_in[2];

  float* out  = (float*)d_out;
  float* nn   = out;
  float* newq = out + BATCH * DIM;
  float* nptr = out + BATCH * DIM + (size_t)QSIZE * DIM;

  u64* ws = (u64*)d_ws;     // 2048 packed (sim, ~idx) slots at offset 0

  const size_t need = 32768 + (size_t)32 * 1024 * 1024;
  dim3 grid(BATCH / 128, 64);

  if (ws_size >= need) {
    // qc in workspace -> newq free from the start -> fuse copy into prep.
    char* qc = (char*)d_ws + 32768;
    prep_kernel<<<4096 + 8192, 256, 0, stream>>>(qx, qc, ws, x, ptr, newq);
    sim_argmax_kernel<<<grid, 256, 0, stream>>>(x, qc, ws);
    gather_kernel<<<(BATCH * DIM) / 256, 256, 0, stream>>>(qx, ptr, ws, nn, nptr);
  } else {
    // fallback: qc aliases newq (verified flow)
    char* qc = (char*)newq;
    prep_kernel<<<4096, 256, 0, stream>>>(qx, qc, ws, x, ptr, newq);
    sim_argmax_kernel<<<grid, 256, 0, stream>>>(x, qc, ws);
    finish_kernel<<<8192 + (BATCH * DIM) / 256, 256, 0, stream>>>(
        x, qx, ptr, ws, nn, newq, nptr);
  }
}